// Round 11
// baseline (866.343 us; speedup 1.0000x reference)
//
#include <hip/hip_runtime.h>
#include <math.h>

// Problem constants: B=4, L=1024, D_IN=128, D_MODEL=512, N_LAYERS=2,
// N_CLASSES=3, D_INNER=1024, D_STATE=64, D_CONV=2, DT_RANK=32, BL=4096.
//
// Precision plan (values shrink ~1000x per layer; final output ~3e-8):
//  - residual h kept fp32 end-to-end (layer-2 h ~3e-8 is f16-subnormal).
//  - y (out_proj A operand) scaled by 2^14 before f16 conversion; out_proj
//    epilogue multiplies by 2^-14 (exact powers of two).

using half8  = __attribute__((ext_vector_type(8))) _Float16;
using half4v = __attribute__((ext_vector_type(4))) _Float16;
using f32x4  = __attribute__((ext_vector_type(4))) float;

#define Y_SCALE 16384.0f   // 2^14

__device__ __forceinline__ float silu_f(float v) {
  return v / (1.f + __expf(-v));
}

__device__ __forceinline__ half8 pack_f16(float4 a, float4 b) {
  half8 r;
  r[0] = (_Float16)a.x; r[1] = (_Float16)a.y; r[2] = (_Float16)a.z; r[3] = (_Float16)a.w;
  r[4] = (_Float16)b.x; r[5] = (_Float16)b.y; r[6] = (_Float16)b.z; r[7] = (_Float16)b.w;
  return r;
}

// ---------------------------------------------------------------------------
// f16 MFMA GEMM, 64 x BN tile. Block 256 thr = 4 waves; wave-tile 32 x (BN/2),
// MI=2 m-frags. BK=32 (one mfma_16x16x32 k-step).
// A: [M][K] row-major, fp32 (AF16=0) or f16 (AF16=1), leading dim lda.
// W: [N][K] fp32 row-major (converted to f16 in staging).
// MODE 0: C per TC/ACT/OF16 (TC=0 -> [M][N]; TC=1 -> [N][M]).
// MODE 1 (fused in_proj, N=2048): n<1024 -> Cv fp32 [M][1024];
//        n>=1024 -> Cv2 f16 silu transposed [n-1024][4096].
// MODE 2 (xproj split, N=160): n<32 -> Cv = dtr fp32 [M][32];
//        32<=n<96 -> Cv2 = BtT fp32 [n-32][4096] (time-major);
//        96<=n<160 -> Cv3 = CtT fp32 [n-96][4096].
//        Branch boundaries (32/96) are multiples of 16 -> fragment-uniform.
// MFMA layouts (m89/m120-verified): A-frag A[m=lane&15][k=q*8+j],
// B-frag B[k=q*8+j][n=lane&15], D: col(n)=lane&15, row(m)=q*4+r.
// ---------------------------------------------------------------------------
template<int AF16, int BN, int TC, int ACT, int OF16, int MODE>
__global__ __launch_bounds__(256)
void gemm_mfma(const void* __restrict__ Av, int lda,
               const float* __restrict__ W,
               const float* __restrict__ bias,
               void* __restrict__ Cv, int ldc,
               int N, int K, float oscale,
               void* __restrict__ Cv2, void* __restrict__ Cv3)
{
  constexpr int NF = BN / 32;            // n-frags per wave
  __shared__ _Float16 As[64 * 40];       // [m][k], row stride 40 f16 (80 B)
  __shared__ _Float16 Ws[BN * 40];       // [n][k]
  const int tid  = threadIdx.x;
  const int lane = tid & 63;
  const int wid  = tid >> 6;
  const int wm   = wid & 1, wn = wid >> 1;   // wave-tile: 32 m x BN/2 n
  const int m0   = blockIdx.y * 64;
  const int n0   = blockIdx.x * BN;
  const int q    = lane >> 4, l16 = lane & 15;

  // A staging: 64 rows, 4 threads/row, 8 halfs each
  const int ar  = tid >> 2;
  const int akq = (tid & 3) * 8;
  // W staging: BN=128: 2 thr/row x 16 halfs; BN=64: 4 thr/row x 8 halfs
  const int wr  = (BN == 128) ? (tid >> 1) : (tid >> 2);
  const int wkq = (BN == 128) ? ((tid & 1) * 16) : ((tid & 3) * 8);
  const int wrow = n0 + wr;
  const bool wv  = (wrow < N);

  const float*    Af = (const float*)Av;
  const _Float16* Ah = (const _Float16*)Av;
  const float*    Wp = W + (size_t)wrow * K;
  const size_t aoff = (size_t)(m0 + ar) * lda + akq;

  float4 raf[2]; half8 rah; float4 rwf[4];
  const float4 zf4 = make_float4(0.f, 0.f, 0.f, 0.f);

  // initial loads (k0 = 0)
  if (AF16) {
    rah = *(const half8*)(Ah + aoff);
  } else {
    const float* p = Af + aoff;
    raf[0] = *(const float4*)p; raf[1] = *(const float4*)(p + 4);
  }
  if (BN == 128) {
    if (wv) {
      const float* p = Wp + wkq;
      rwf[0] = *(const float4*)p;       rwf[1] = *(const float4*)(p + 4);
      rwf[2] = *(const float4*)(p + 8); rwf[3] = *(const float4*)(p + 12);
    } else { rwf[0] = rwf[1] = rwf[2] = rwf[3] = zf4; }
  } else {
    if (wv) {
      const float* p = Wp + wkq;
      rwf[0] = *(const float4*)p; rwf[1] = *(const float4*)(p + 4);
    } else { rwf[0] = rwf[1] = zf4; }
  }

  f32x4 acc[2][NF];
  #pragma unroll
  for (int mi = 0; mi < 2; ++mi)
    #pragma unroll
    for (int ni = 0; ni < NF; ++ni)
      acc[mi][ni] = (f32x4){0.f, 0.f, 0.f, 0.f};

  for (int k0 = 0; k0 < K; k0 += 32) {
    if (k0) __syncthreads();
    if (AF16) *(half8*)&As[ar * 40 + akq] = rah;
    else      *(half8*)&As[ar * 40 + akq] = pack_f16(raf[0], raf[1]);
    if (BN == 128) {
      *(half8*)&Ws[wr * 40 + wkq]     = pack_f16(rwf[0], rwf[1]);
      *(half8*)&Ws[wr * 40 + wkq + 8] = pack_f16(rwf[2], rwf[3]);
    } else {
      *(half8*)&Ws[wr * 40 + wkq]     = pack_f16(rwf[0], rwf[1]);
    }
    __syncthreads();

    if (k0 + 32 < K) {            // prefetch next chunk
      const int kn = k0 + 32;
      if (AF16) {
        rah = *(const half8*)(Ah + aoff + kn);
      } else {
        const float* p = Af + aoff + kn;
        raf[0] = *(const float4*)p; raf[1] = *(const float4*)(p + 4);
      }
      if (BN == 128) {
        if (wv) {
          const float* p = Wp + kn + wkq;
          rwf[0] = *(const float4*)p;       rwf[1] = *(const float4*)(p + 4);
          rwf[2] = *(const float4*)(p + 8); rwf[3] = *(const float4*)(p + 12);
        }
      } else {
        if (wv) {
          const float* p = Wp + kn + wkq;
          rwf[0] = *(const float4*)p; rwf[1] = *(const float4*)(p + 4);
        }
      }
    }

    half8 af[2], wf[NF];
    #pragma unroll
    for (int mi = 0; mi < 2; ++mi)
      af[mi] = *(const half8*)&As[(wm * 32 + mi * 16 + l16) * 40 + q * 8];
    #pragma unroll
    for (int ni = 0; ni < NF; ++ni)
      wf[ni] = *(const half8*)&Ws[(wn * (BN / 2) + ni * 16 + l16) * 40 + q * 8];
    #pragma unroll
    for (int mi = 0; mi < 2; ++mi)
      #pragma unroll
      for (int ni = 0; ni < NF; ++ni)
        acc[mi][ni] = __builtin_amdgcn_mfma_f32_16x16x32_f16(af[mi], wf[ni],
                                                             acc[mi][ni], 0, 0, 0);
  }

  float*    Cf = (float*)Cv;
  _Float16* Ch = (_Float16*)Cv;

  if (MODE == 1) {
    // fused in_proj epilogue: branch is fragment-uniform
    _Float16* Ch2 = (_Float16*)Cv2;
    #pragma unroll
    for (int ni = 0; ni < NF; ++ni) {
      const int n = n0 + wn * (BN / 2) + ni * 16 + l16;
      if (n < 1024) {
        #pragma unroll
        for (int mi = 0; mi < 2; ++mi) {
          const int mb = m0 + wm * 32 + mi * 16 + q * 4;
          #pragma unroll
          for (int r = 0; r < 4; ++r)
            Cf[(size_t)(mb + r) * 1024 + n] = acc[mi][ni][r];
        }
      } else {
        const int nn = n - 1024;
        #pragma unroll
        for (int mi = 0; mi < 2; ++mi) {
          const int mb = m0 + wm * 32 + mi * 16 + q * 4;
          half4v h4;
          #pragma unroll
          for (int r = 0; r < 4; ++r) h4[r] = (_Float16)silu_f(acc[mi][ni][r]);
          *(half4v*)&Ch2[(size_t)nn * 4096 + mb] = h4;
        }
      }
    }
    return;
  }

  if (MODE == 2) {
    // xproj split epilogue: dtr [M][32] + BtT/CtT [64][4096] time-major
    float* Bt = (float*)Cv2;
    float* Ct = (float*)Cv3;
    #pragma unroll
    for (int ni = 0; ni < NF; ++ni) {
      const int n = n0 + wn * (BN / 2) + ni * 16 + l16;
      if (n < 32) {
        #pragma unroll
        for (int mi = 0; mi < 2; ++mi) {
          const int mb = m0 + wm * 32 + mi * 16 + q * 4;
          #pragma unroll
          for (int r = 0; r < 4; ++r)
            Cf[(size_t)(mb + r) * 32 + n] = acc[mi][ni][r];
        }
      } else if (n < 96) {
        #pragma unroll
        for (int mi = 0; mi < 2; ++mi) {
          const int mb = m0 + wm * 32 + mi * 16 + q * 4;
          *(float4*)&Bt[(size_t)(n - 32) * 4096 + mb] =
            make_float4(acc[mi][ni][0], acc[mi][ni][1],
                        acc[mi][ni][2], acc[mi][ni][3]);
        }
      } else if (n < 160) {
        #pragma unroll
        for (int mi = 0; mi < 2; ++mi) {
          const int mb = m0 + wm * 32 + mi * 16 + q * 4;
          *(float4*)&Ct[(size_t)(n - 96) * 4096 + mb] =
            make_float4(acc[mi][ni][0], acc[mi][ni][1],
                        acc[mi][ni][2], acc[mi][ni][3]);
        }
      }
    }
    return;
  }

  // MODE 0 epilogue
  #pragma unroll
  for (int ni = 0; ni < NF; ++ni) {
    const int n = n0 + wn * (BN / 2) + ni * 16 + l16;
    if (n < N) {
      const float bv = (bias != nullptr) ? bias[n] : 0.f;
      #pragma unroll
      for (int mi = 0; mi < 2; ++mi) {
        const int mb = m0 + wm * 32 + mi * 16 + q * 4;
        float o[4];
        #pragma unroll
        for (int r = 0; r < 4; ++r) {
          float v = acc[mi][ni][r] * oscale + bv;
          if (ACT == 1) v = (v > 20.f) ? v : log1pf(__expf(v));
          if (ACT == 2) v = silu_f(v);
          o[r] = v;
        }
        if (TC == 0) {
          #pragma unroll
          for (int r = 0; r < 4; ++r) {
            size_t off = (size_t)(mb + r) * ldc + n;
            if (OF16) Ch[off] = (_Float16)o[r];
            else      Cf[off] = o[r];
          }
        } else {
          size_t off = (size_t)n * ldc + mb;
          if (OF16) {
            half4v h4; h4[0]=(_Float16)o[0]; h4[1]=(_Float16)o[1];
                       h4[2]=(_Float16)o[2]; h4[3]=(_Float16)o[3];
            *(half4v*)&Ch[off] = h4;
          } else {
            *(float4*)&Cf[off] = make_float4(o[0], o[1], o[2], o[3]);
          }
        }
      }
    }
  }
}

// ---------------------------------------------------------------------------
// Depthwise causal conv (D_CONV=2) + silu, 64x64 LDS transpose.
// in : xcp [4096 bl][1024 d] fp32
// out: xcT [1024 d][4096 bl] fp32 (scan input)  +  xcf [4096 bl][1024 d] f16
// ---------------------------------------------------------------------------
__global__ void conv_t_kernel(const float* __restrict__ xcp,
                              const float* __restrict__ cw,   // [1024][2]
                              const float* __restrict__ cb,   // [1024]
                              float* __restrict__ xcT,
                              _Float16* __restrict__ xcf)
{
  __shared__ float tile[64][65];
  const int blk = blockIdx.x;            // b*256 + tt*16 + dd
  const int b  = blk >> 8;
  const int tt = (blk >> 4) & 15;
  const int dd = blk & 15;
  const int t0 = tt * 64, d0 = dd * 64;
  const int tid = threadIdx.x;

  #pragma unroll
  for (int i = 0; i < 16; ++i) {
    int idx = i * 256 + tid;
    int t = idx >> 6, d = idx & 63;
    int gt = t0 + t;
    size_t rcur = ((size_t)(b * 1024 + gt) << 10) + d0 + d;
    float cur  = xcp[rcur];
    float prev = (gt > 0) ? xcp[rcur - 1024] : 0.f;
    float v = fmaf(prev, cw[(d0+d)*2], fmaf(cur, cw[(d0+d)*2 + 1], cb[d0+d]));
    float sv = silu_f(v);
    tile[t][d] = sv;
    xcf[rcur] = (_Float16)sv;
  }
  __syncthreads();
  #pragma unroll
  for (int i = 0; i < 16; ++i) {
    int idx = i * 256 + tid;
    int d = idx >> 6, t = idx & 63;
    xcT[((size_t)(d0 + d) << 12) + b * 1024 + t0 + t] = tile[t][d];
  }
}

// ---------------------------------------------------------------------------
// Transpose + f16 convert WITH 2^14 scaling:
// src [1024 d][4096 bl] fp32 -> dst [4096 bl][1024 d] f16, dst = src * 16384.
// ---------------------------------------------------------------------------
__global__ void trans_f16_kernel(const float* __restrict__ src,
                                 _Float16* __restrict__ dst)
{
  __shared__ float tile[64][65];
  const int bl0 = blockIdx.x * 64;
  const int d0  = blockIdx.y * 64;
  const int tid = threadIdx.x;
  #pragma unroll
  for (int i = 0; i < 16; ++i) {
    int idx = i * 256 + tid;
    int r = idx >> 6, c = idx & 63;     // r: d, c: bl
    tile[r][c] = src[((size_t)(d0 + r) << 12) + bl0 + c];
  }
  __syncthreads();
  #pragma unroll
  for (int i = 0; i < 16; ++i) {
    int idx = i * 256 + tid;
    int c = idx >> 6, r = idx & 63;     // write rows bl, cols d
    dst[((size_t)(bl0 + c) << 10) + d0 + r] = (_Float16)(tile[r][c] * Y_SCALE);
  }
}

// ---------------------------------------------------------------------------
// Selective scan, time-major. One wave per (b,d), lane = s (D_STATE=64).
// R11: BARRIER-FREE. B/C arrive pre-transposed time-major (BtT/CtT [64][4096]
// from xproj's MODE-2 epilogue): lane s reads its own row — 4 dwordx4/chunk,
// one 64B L2-resident cache line per lane per tensor. No block-shared LDS,
// no __syncthreads (the P reduction tile is wave-private; lgkmcnt suffices,
// as in all prior rounds). DS ops/chunk: 56 -> 22. 16 waves/CU self-schedule.
// y = (scan + x*Dp) * silu(z) written IN PLACE over xcT.
// ---------------------------------------------------------------------------
__global__ __launch_bounds__(256, 4)
void scan_kernel(const float* __restrict__ dtT,     // [1024][4096]
                 float* __restrict__ xcT,           // [1024][4096]; y in place
                 const _Float16* __restrict__ zsT,  // [1024][4096], silu(z), f16
                 const float* __restrict__ BtT,     // [64 s][4096 bl]
                 const float* __restrict__ CtT,     // [64 s][4096 bl]
                 const float* __restrict__ A_log,   // [1024][64]
                 const float* __restrict__ Dp)      // [1024]
{
  __shared__ float P[4][16][68];       // per-wave reduction tile (wave-private)
  const int tid  = threadIdx.x;
  const int lane = tid & 63;
  const int wrp  = tid >> 6;
  const int wid  = __builtin_amdgcn_readfirstlane(blockIdx.x * 4 + wrp);
  const int b = wid >> 10;
  const int d = wid & 1023;
  float (*Pw)[68] = P[wrp];

  const float a   = -__expf(A_log[d*64 + lane]);
  const float dpv = Dp[d];
  const size_t row = ((size_t)d << 12) + b * 1024;
  const float*    dtp = dtT + row;
  float*          xyp = xcT + row;
  const _Float16* zsp = zsT + row;
  const float*    bp  = BtT + ((size_t)lane << 12) + b * 1024;  // own row
  const float*    cp  = CtT + ((size_t)lane << 12) + b * 1024;

  const int tt_r = lane >> 2;          // which timestep this lane reduces
  const int c0   = (lane & 3) << 4;    // which 16-state chunk

  float h = 0.f;
  for (int t0 = 0; t0 < 1024; t0 += 16) {
    // ---- all chunk loads upfront (pipelined; TLP hides latency) ----
    float4 bq[4], cq[4], dq[4], xq[4];
    #pragma unroll
    for (int i = 0; i < 4; ++i) {
      bq[i] = *(const float4*)(bp  + t0 + i*4);
      cq[i] = *(const float4*)(cp  + t0 + i*4);
      dq[i] = *(const float4*)(dtp + t0 + i*4);
      xq[i] = *(const float4*)(xyp + t0 + i*4);
    }
    float zs  = (float)zsp[t0 + tt_r];
    float xvl = xyp[t0 + tt_r];          // this lane's x (read before y store)
    const float* Bv  = reinterpret_cast<const float*>(bq);
    const float* Cv  = reinterpret_cast<const float*>(cq);
    const float* dtv = reinterpret_cast<const float*>(dq);
    const float* xv  = reinterpret_cast<const float*>(xq);

    // ---- parallel phase: the exps (quarter-rate, batched) ----
    float dA[16];
    #pragma unroll
    for (int tt = 0; tt < 16; ++tt) dA[tt] = __expf(dtv[tt] * a);

    // ---- serial recurrence (scheduler hoists the h-independent muls) ----
    #pragma unroll
    for (int tt = 0; tt < 16; ++tt) {
      h = fmaf(h, dA[tt], dtv[tt] * xv[tt] * Bv[tt]);
      Pw[tt][lane] = h * Cv[tt];
    }

    // ---- batched reduction: lane L sums 16 states of timestep L>>2 ----
    float4 s0 = *(const float4*)&Pw[tt_r][c0];
    float4 s1 = *(const float4*)&Pw[tt_r][c0 + 4];
    float4 s2 = *(const float4*)&Pw[tt_r][c0 + 8];
    float4 s3 = *(const float4*)&Pw[tt_r][c0 + 12];
    float r = ((s0.x + s0.y) + (s0.z + s0.w))
            + ((s1.x + s1.y) + (s1.z + s1.w))
            + ((s2.x + s2.y) + (s2.z + s2.w))
            + ((s3.x + s3.y) + (s3.z + s3.w));
    r += __shfl_xor(r, 1, 64);
    r += __shfl_xor(r, 2, 64);
    if ((lane & 3) == 0)
      xyp[t0 + tt_r] = fmaf(xvl, dpv, r) * zs;
    // no __syncthreads: P is wave-private, ordered by lgkmcnt.
  }
}

// out[b,c] = h[b,L-1,:] . fc_w[c,:] + fc_b[c]; h is fp32 [4096][512]
__global__ void head_kernel(const float* __restrict__ h,
                            const float* __restrict__ fc_w,
                            const float* __restrict__ fc_b,
                            float* __restrict__ out)
{
  int bc = blockIdx.x;            // 0..11
  int b = bc / 3, c = bc % 3;
  int lane = threadIdx.x;
  const float* hr = h + (size_t)(b*1024 + 1023) * 512;
  const float* wr = fc_w + c*512;
  float s = 0.f;
  #pragma unroll
  for (int i = 0; i < 8; ++i) s = fmaf(hr[lane + i*64], wr[lane + i*64], s);
  #pragma unroll
  for (int o = 32; o > 0; o >>= 1) s += __shfl_xor(s, o, 64);
  if (lane == 0) out[b*3 + c] = s + fc_b[c];
}

extern "C" void kernel_launch(void* const* d_in, const int* in_sizes, int n_in,
                              void* d_out, int out_size, void* d_ws, size_t ws_size,
                              hipStream_t stream)
{
  const float* x        = (const float*)d_in[0];
  const float* exp_w    = (const float*)d_in[1];
  const float* exp_b    = (const float*)d_in[2];
  const float* in_w     = (const float*)d_in[3];
  const float* conv_w   = (const float*)d_in[4];
  const float* conv_b   = (const float*)d_in[5];
  const float* xproj_w  = (const float*)d_in[6];
  const float* dtproj_w = (const float*)d_in[7];
  const float* dtproj_b = (const float*)d_in[8];
  const float* A_log    = (const float*)d_in[9];
  const float* Dp       = (const float*)d_in[10];
  const float* out_w    = (const float*)d_in[11];
  const float* fc_w     = (const float*)d_in[12];
  const float* fc_b     = (const float*)d_in[13];
  float* out = (float*)d_out;

  // Workspace layout (byte offsets), 59 MB total. The 8..24 MB region is
  // sequentially reused: xcpre (in_proj -> conv_t) -> dtT (dtproj -> scan)
  // -> y16 (trans_f16 -> out_proj).
  char* ws = (char*)d_ws;
  float*    hf    = (float*)   (ws);                          //  8 MB [4096][512] fp32
  float*    xcpre = (float*)   (ws + ((size_t)8  << 20));     // 16 MB [4096][1024]
  float*    dtT   = (float*)   (ws + ((size_t)8  << 20));     // 16 MB [1024][4096] (reuse)
  _Float16* y16   = (_Float16*)(ws + ((size_t)8  << 20));     //  8 MB [4096][1024] (reuse)
  float*    xcT   = (float*)   (ws + ((size_t)24 << 20));     // 16 MB [1024][4096]
  _Float16* zsT   = (_Float16*)(ws + ((size_t)40 << 20));     //  8 MB [1024][4096]
  float*    dtr   = (float*)   (ws + ((size_t)48 << 20));     //  0.5 MB [4096][32]
  float*    BtT   = (float*)   (ws + ((size_t)49 << 20));     //  1 MB [64][4096]
  float*    CtT   = (float*)   (ws + ((size_t)50 << 20));     //  1 MB [64][4096]
  _Float16* xc16  = (_Float16*)(ws + ((size_t)51 << 20));     //  8 MB [4096][1024]

  dim3 blk(256);

  // expand: hf = x @ exp_w^T + exp_b   [4096,512] K=128, fp32 out. 512 blocks.
  gemm_mfma<0,64,0,0,0,0><<<dim3(8,64), blk, 0, stream>>>(x, 128, exp_w, exp_b,
                                                          hf, 512, 512, 128, 1.f,
                                                          nullptr, nullptr);

  for (int l = 0; l < 2; ++l) {
    const float* inw = in_w + (size_t)l * 2048 * 512;
    // fused in_proj: xcpre [4096][1024] f32 + zsT [1024][4096] silu f16.
    // N=2048 K=512. 1024 blocks (4/CU).
    gemm_mfma<0,128,0,0,0,1><<<dim3(16,64), blk, 0, stream>>>(hf, 512, inw, nullptr,
                                                              xcpre, 1024, 2048, 512, 1.f,
                                                              zsT, nullptr);
    // conv + silu -> xcT (fp32, scan) + xc16 (f16, xproj A)
    conv_t_kernel<<<1024, blk, 0, stream>>>(xcpre, conv_w + l*2048, conv_b + l*1024,
                                            xcT, xc16);
    // xproj (MODE 2): dtr [4096][32] + BtT/CtT [64][4096]. K=1024. 192 blocks.
    gemm_mfma<1,64,0,0,0,2><<<dim3(3,64), blk, 0, stream>>>(xc16, 1024,
                                                            xproj_w + (size_t)l*160*1024,
                                                            nullptr, dtr, 32, 160, 1024,
                                                            1.f, BtT, CtT);
    // dtproj (transposed + softplus): dtT [1024][4096], A=dtr lda=32, K=32.
    gemm_mfma<0,64,1,1,0,0><<<dim3(16,64), blk, 0, stream>>>(dtr, 32,
                                                             dtproj_w + (size_t)l*1024*32,
                                                             dtproj_b + l*1024,
                                                             dtT, 4096, 1024, 32, 1.f,
                                                             nullptr, nullptr);
    // selective scan (barrier-free); y = (scan + x*Dp)*silu(z) over xcT
    scan_kernel<<<1024, blk, 0, stream>>>(dtT, xcT, zsT, BtT, CtT,
                                          A_log + (size_t)l*65536, Dp + l*1024);
    // y -> y16 = f16(y * 2^14) [4096][1024]   (overwrites dtT — dead)
    trans_f16_kernel<<<dim3(64,16), blk, 0, stream>>>(xcT, y16);
    // out_proj: hf = (y16 @ out_w^T) * 2^-14   [4096,512] K=1024. 512 blocks.
    gemm_mfma<1,64,0,0,0,0><<<dim3(8,64), blk, 0, stream>>>(y16, 1024,
                                                            out_w + (size_t)l*512*1024,
                                                            nullptr, hf, 512, 512, 1024,
                                                            1.f / Y_SCALE, nullptr, nullptr);
  }

  head_kernel<<<12, 64, 0, stream>>>(hf, fc_w, fc_b, out);
}

// Round 12
// 506.825 us; speedup vs baseline: 1.7094x; 1.7094x over previous
//
#include <hip/hip_runtime.h>
#include <math.h>

// Problem constants: B=4, L=1024, D_IN=128, D_MODEL=512, N_LAYERS=2,
// N_CLASSES=3, D_INNER=1024, D_STATE=64, D_CONV=2, DT_RANK=32, BL=4096.
//
// Precision plan (values shrink ~1000x per layer; final output ~3e-8):
//  - residual h kept fp32 end-to-end (layer-2 h ~3e-8 is f16-subnormal).
//  - y scaled by 2^14 at f16 conversion (in the scan store); out_proj
//    epilogue multiplies by 2^-14 (exact powers of two).
//
// R11 lesson (reverted): per-lane 16KB-strided B/C rows destroyed coalescing
// (64 lines/wave-load, L2 channel camping, scan 125->305 us). R12 restores
// the R9 dbc + LDS-staged + barriered scan, adds an XCD swizzle and folds
// the y->f16 transpose into the scan store (kills trans_f16 entirely).

using half8  = __attribute__((ext_vector_type(8))) _Float16;
using half4v = __attribute__((ext_vector_type(4))) _Float16;
using f32x4  = __attribute__((ext_vector_type(4))) float;

#define Y_SCALE 16384.0f   // 2^14

__device__ __forceinline__ float silu_f(float v) {
  return v / (1.f + __expf(-v));
}

__device__ __forceinline__ half8 pack_f16(float4 a, float4 b) {
  half8 r;
  r[0] = (_Float16)a.x; r[1] = (_Float16)a.y; r[2] = (_Float16)a.z; r[3] = (_Float16)a.w;
  r[4] = (_Float16)b.x; r[5] = (_Float16)b.y; r[6] = (_Float16)b.z; r[7] = (_Float16)b.w;
  return r;
}

// ---------------------------------------------------------------------------
// f16 MFMA GEMM, 64 x BN tile. Block 256 thr = 4 waves; wave-tile 32 x (BN/2),
// MI=2 m-frags. BK=32 (one mfma_16x16x32 k-step).
// A: [M][K] row-major, fp32 (AF16=0) or f16 (AF16=1), leading dim lda.
// W: [N][K] fp32 row-major (converted to f16 in staging).
// MODE 0: C per TC/ACT/OF16 (TC=0 -> [M][N]; TC=1 -> [N][M]).
// MODE 1 (fused in_proj, N=2048): n<1024 -> Cv fp32 [M][1024];
//        n>=1024 -> Cv2 f16 silu transposed [n-1024][4096].
// MFMA layouts (m89/m120-verified): A-frag A[m=lane&15][k=q*8+j],
// B-frag B[k=q*8+j][n=lane&15], D: col(n)=lane&15, row(m)=q*4+r.
// ---------------------------------------------------------------------------
template<int AF16, int BN, int TC, int ACT, int OF16, int MODE>
__global__ __launch_bounds__(256)
void gemm_mfma(const void* __restrict__ Av, int lda,
               const float* __restrict__ W,
               const float* __restrict__ bias,
               void* __restrict__ Cv, int ldc,
               int N, int K, float oscale,
               void* __restrict__ Cv2)
{
  constexpr int NF = BN / 32;            // n-frags per wave
  __shared__ _Float16 As[64 * 40];       // [m][k], row stride 40 f16 (80 B)
  __shared__ _Float16 Ws[BN * 40];       // [n][k]
  const int tid  = threadIdx.x;
  const int lane = tid & 63;
  const int wid  = tid >> 6;
  const int wm   = wid & 1, wn = wid >> 1;   // wave-tile: 32 m x BN/2 n
  const int m0   = blockIdx.y * 64;
  const int n0   = blockIdx.x * BN;
  const int q    = lane >> 4, l16 = lane & 15;

  // A staging: 64 rows, 4 threads/row, 8 halfs each
  const int ar  = tid >> 2;
  const int akq = (tid & 3) * 8;
  // W staging: BN=128: 2 thr/row x 16 halfs; BN=64: 4 thr/row x 8 halfs
  const int wr  = (BN == 128) ? (tid >> 1) : (tid >> 2);
  const int wkq = (BN == 128) ? ((tid & 1) * 16) : ((tid & 3) * 8);
  const int wrow = n0 + wr;
  const bool wv  = (wrow < N);

  const float*    Af = (const float*)Av;
  const _Float16* Ah = (const _Float16*)Av;
  const float*    Wp = W + (size_t)wrow * K;
  const size_t aoff = (size_t)(m0 + ar) * lda + akq;

  float4 raf[2]; half8 rah; float4 rwf[4];
  const float4 zf4 = make_float4(0.f, 0.f, 0.f, 0.f);

  // initial loads (k0 = 0)
  if (AF16) {
    rah = *(const half8*)(Ah + aoff);
  } else {
    const float* p = Af + aoff;
    raf[0] = *(const float4*)p; raf[1] = *(const float4*)(p + 4);
  }
  if (BN == 128) {
    if (wv) {
      const float* p = Wp + wkq;
      rwf[0] = *(const float4*)p;       rwf[1] = *(const float4*)(p + 4);
      rwf[2] = *(const float4*)(p + 8); rwf[3] = *(const float4*)(p + 12);
    } else { rwf[0] = rwf[1] = rwf[2] = rwf[3] = zf4; }
  } else {
    if (wv) {
      const float* p = Wp + wkq;
      rwf[0] = *(const float4*)p; rwf[1] = *(const float4*)(p + 4);
    } else { rwf[0] = rwf[1] = zf4; }
  }

  f32x4 acc[2][NF];
  #pragma unroll
  for (int mi = 0; mi < 2; ++mi)
    #pragma unroll
    for (int ni = 0; ni < NF; ++ni)
      acc[mi][ni] = (f32x4){0.f, 0.f, 0.f, 0.f};

  for (int k0 = 0; k0 < K; k0 += 32) {
    if (k0) __syncthreads();
    if (AF16) *(half8*)&As[ar * 40 + akq] = rah;
    else      *(half8*)&As[ar * 40 + akq] = pack_f16(raf[0], raf[1]);
    if (BN == 128) {
      *(half8*)&Ws[wr * 40 + wkq]     = pack_f16(rwf[0], rwf[1]);
      *(half8*)&Ws[wr * 40 + wkq + 8] = pack_f16(rwf[2], rwf[3]);
    } else {
      *(half8*)&Ws[wr * 40 + wkq]     = pack_f16(rwf[0], rwf[1]);
    }
    __syncthreads();

    if (k0 + 32 < K) {            // prefetch next chunk
      const int kn = k0 + 32;
      if (AF16) {
        rah = *(const half8*)(Ah + aoff + kn);
      } else {
        const float* p = Af + aoff + kn;
        raf[0] = *(const float4*)p; raf[1] = *(const float4*)(p + 4);
      }
      if (BN == 128) {
        if (wv) {
          const float* p = Wp + kn + wkq;
          rwf[0] = *(const float4*)p;       rwf[1] = *(const float4*)(p + 4);
          rwf[2] = *(const float4*)(p + 8); rwf[3] = *(const float4*)(p + 12);
        }
      } else {
        if (wv) {
          const float* p = Wp + kn + wkq;
          rwf[0] = *(const float4*)p; rwf[1] = *(const float4*)(p + 4);
        }
      }
    }

    half8 af[2], wf[NF];
    #pragma unroll
    for (int mi = 0; mi < 2; ++mi)
      af[mi] = *(const half8*)&As[(wm * 32 + mi * 16 + l16) * 40 + q * 8];
    #pragma unroll
    for (int ni = 0; ni < NF; ++ni)
      wf[ni] = *(const half8*)&Ws[(wn * (BN / 2) + ni * 16 + l16) * 40 + q * 8];
    #pragma unroll
    for (int mi = 0; mi < 2; ++mi)
      #pragma unroll
      for (int ni = 0; ni < NF; ++ni)
        acc[mi][ni] = __builtin_amdgcn_mfma_f32_16x16x32_f16(af[mi], wf[ni],
                                                             acc[mi][ni], 0, 0, 0);
  }

  float*    Cf = (float*)Cv;
  _Float16* Ch = (_Float16*)Cv;

  if (MODE == 1) {
    // fused in_proj epilogue: branch is fragment-uniform
    _Float16* Ch2 = (_Float16*)Cv2;
    #pragma unroll
    for (int ni = 0; ni < NF; ++ni) {
      const int n = n0 + wn * (BN / 2) + ni * 16 + l16;
      if (n < 1024) {
        #pragma unroll
        for (int mi = 0; mi < 2; ++mi) {
          const int mb = m0 + wm * 32 + mi * 16 + q * 4;
          #pragma unroll
          for (int r = 0; r < 4; ++r)
            Cf[(size_t)(mb + r) * 1024 + n] = acc[mi][ni][r];
        }
      } else {
        const int nn = n - 1024;
        #pragma unroll
        for (int mi = 0; mi < 2; ++mi) {
          const int mb = m0 + wm * 32 + mi * 16 + q * 4;
          half4v h4;
          #pragma unroll
          for (int r = 0; r < 4; ++r) h4[r] = (_Float16)silu_f(acc[mi][ni][r]);
          *(half4v*)&Ch2[(size_t)nn * 4096 + mb] = h4;
        }
      }
    }
    return;
  }

  // MODE 0 epilogue
  #pragma unroll
  for (int ni = 0; ni < NF; ++ni) {
    const int n = n0 + wn * (BN / 2) + ni * 16 + l16;
    if (n < N) {
      const float bv = (bias != nullptr) ? bias[n] : 0.f;
      #pragma unroll
      for (int mi = 0; mi < 2; ++mi) {
        const int mb = m0 + wm * 32 + mi * 16 + q * 4;
        float o[4];
        #pragma unroll
        for (int r = 0; r < 4; ++r) {
          float v = acc[mi][ni][r] * oscale + bv;
          if (ACT == 1) v = (v > 20.f) ? v : log1pf(__expf(v));
          if (ACT == 2) v = silu_f(v);
          o[r] = v;
        }
        if (TC == 0) {
          #pragma unroll
          for (int r = 0; r < 4; ++r) {
            size_t off = (size_t)(mb + r) * ldc + n;
            if (OF16) Ch[off] = (_Float16)o[r];
            else      Cf[off] = o[r];
          }
        } else {
          size_t off = (size_t)n * ldc + mb;
          if (OF16) {
            half4v h4; h4[0]=(_Float16)o[0]; h4[1]=(_Float16)o[1];
                       h4[2]=(_Float16)o[2]; h4[3]=(_Float16)o[3];
            *(half4v*)&Ch[off] = h4;
          } else {
            *(float4*)&Cf[off] = make_float4(o[0], o[1], o[2], o[3]);
          }
        }
      }
    }
  }
}

// ---------------------------------------------------------------------------
// Depthwise causal conv (D_CONV=2) + silu, 64x64 LDS transpose.
// in : xcp [4096 bl][1024 d] fp32
// out: xcT [1024 d][4096 bl] fp32 (scan input)  +  xcf [4096 bl][1024 d] f16
// ---------------------------------------------------------------------------
__global__ void conv_t_kernel(const float* __restrict__ xcp,
                              const float* __restrict__ cw,   // [1024][2]
                              const float* __restrict__ cb,   // [1024]
                              float* __restrict__ xcT,
                              _Float16* __restrict__ xcf)
{
  __shared__ float tile[64][65];
  const int blk = blockIdx.x;            // b*256 + tt*16 + dd
  const int b  = blk >> 8;
  const int tt = (blk >> 4) & 15;
  const int dd = blk & 15;
  const int t0 = tt * 64, d0 = dd * 64;
  const int tid = threadIdx.x;

  #pragma unroll
  for (int i = 0; i < 16; ++i) {
    int idx = i * 256 + tid;
    int t = idx >> 6, d = idx & 63;
    int gt = t0 + t;
    size_t rcur = ((size_t)(b * 1024 + gt) << 10) + d0 + d;
    float cur  = xcp[rcur];
    float prev = (gt > 0) ? xcp[rcur - 1024] : 0.f;
    float v = fmaf(prev, cw[(d0+d)*2], fmaf(cur, cw[(d0+d)*2 + 1], cb[d0+d]));
    float sv = silu_f(v);
    tile[t][d] = sv;
    xcf[rcur] = (_Float16)sv;
  }
  __syncthreads();
  #pragma unroll
  for (int i = 0; i < 16; ++i) {
    int idx = i * 256 + tid;
    int d = idx >> 6, t = idx & 63;
    xcT[((size_t)(d0 + d) << 12) + b * 1024 + t0 + t] = tile[t][d];
  }
}

// ---------------------------------------------------------------------------
// Selective scan, time-major. One wave per (b,d), lane = s (D_STATE=64).
// R9-proven core: B/C block-shared in LDS (double-buffered; 4 waves share b),
// one barrier/chunk, wave-private P reduction tile.
// R12: (a) XCD swizzle — blockIdx%8 round-robins XCDs, so remap gives each
// XCD a contiguous d-range and a single b (dbc set/XCD = 640 KB, fits L2;
// y16 scatter lines stay XCD-local). (b) y stored DIRECTLY as f16 [bl][d]
// (x Y_SCALE, exact 2^14), killing the trans_f16 kernel; xcT is read-only.
// ---------------------------------------------------------------------------
__global__ __launch_bounds__(256, 4)
void scan_kernel(const float* __restrict__ dtT,     // [1024][4096]
                 const float* __restrict__ xcT,     // [1024][4096]
                 const _Float16* __restrict__ zsT,  // [1024][4096], silu(z), f16
                 const float* __restrict__ dbc,     // [B][1024][160]; B@+32, C@+96
                 const float* __restrict__ A_log,   // [1024][64]
                 const float* __restrict__ Dp,      // [1024]
                 _Float16* __restrict__ y16)        // [4096 bl][1024 d], y*2^14
{
  __shared__ float P[4][16][68];       // per-wave reduction tile
  __shared__ float BC[2][2][16][64];   // [buf][B/C][t][s], block-shared
  const int tid  = threadIdx.x;
  const int lane = tid & 63;
  const int wrp  = tid >> 6;
  // XCD swizzle: consecutive blockIdx round-robin XCDs; remap so each XCD
  // covers a contiguous bswz range -> contiguous d, single b.
  const int rb   = blockIdx.x;
  const int bswz = ((rb & 7) << 7) | (rb >> 3);          // 0..1023 bijective
  const int wid  = __builtin_amdgcn_readfirstlane(bswz * 4 + wrp);
  const int b = wid >> 10;             // block-uniform
  const int d = wid & 1023;
  float (*Pw)[68] = P[wrp];

  const float a   = -__expf(A_log[d*64 + lane]);
  const float dpv = Dp[d];
  const size_t row = ((size_t)d << 12) + b * 1024;
  const float*    dtp = dtT + row;
  const float*    xp  = xcT + row;
  const _Float16* zsp = zsT + row;
  _Float16*       yp  = y16 + ((size_t)b << 20) + d;     // + t*1024

  // cooperative B/C staging coords: thread -> (t in chunk, s-quad)
  const int ct = tid >> 4;             // 0..15
  const int cs = (tid & 15) * 4;       // 0..60
  const float* bcbase = dbc + (size_t)b * 163840 + (size_t)ct * 160 + cs;

  const int tt_r = lane >> 2;          // which timestep this lane reduces
  const int c0   = (lane & 3) << 4;    // which 16-state chunk

  // preload chunk 0 into buf 0
  {
    *(float4*)&BC[0][0][ct][cs] = *(const float4*)(bcbase + 32);
    *(float4*)&BC[0][1][ct][cs] = *(const float4*)(bcbase + 96);
  }
  __syncthreads();

  float h = 0.f;
  for (int t0 = 0; t0 < 1024; t0 += 16) {
    const int p = (t0 >> 4) & 1;
    // ---- issue next chunk's global loads first (latency overlaps compute) --
    const int tn = (t0 + 16 < 1024) ? (t0 + 16) : t0;
    float4 nb = *(const float4*)(bcbase + (size_t)tn * 160 + 32);
    float4 nc = *(const float4*)(bcbase + (size_t)tn * 160 + 96);

    // ---- per-wave loads for current chunk ----
    float4 dq[4], xq[4];
    #pragma unroll
    for (int i = 0; i < 4; ++i) {
      dq[i] = *(const float4*)(dtp + t0 + i*4);
      xq[i] = *(const float4*)(xp  + t0 + i*4);
    }
    float zs  = (float)zsp[t0 + tt_r] * Y_SCALE;   // exact 2^14 fold
    float xvl = xp[t0 + tt_r];                     // this lane's x for Dp
    const float* dtv = reinterpret_cast<const float*>(dq);
    const float* xv  = reinterpret_cast<const float*>(xq);

    // ---- parallel phase: everything h-independent ----
    float dA[16], ub[16], Cv[16];
    #pragma unroll
    for (int tt = 0; tt < 16; ++tt) {
      float Bv = BC[p][0][tt][lane];
      Cv[tt]   = BC[p][1][tt][lane];
      dA[tt] = __expf(dtv[tt] * a);
      ub[tt] = dtv[tt] * xv[tt] * Bv;
    }
    // ---- serial recurrence: fma -> mul -> ds_write per t ----
    #pragma unroll
    for (int tt = 0; tt < 16; ++tt) {
      h = fmaf(h, dA[tt], ub[tt]);
      Pw[tt][lane] = h * Cv[tt];
    }

    // ---- batched reduction: lane L sums 16 states of timestep L>>2 ----
    float4 s0 = *(const float4*)&Pw[tt_r][c0];
    float4 s1 = *(const float4*)&Pw[tt_r][c0 + 4];
    float4 s2 = *(const float4*)&Pw[tt_r][c0 + 8];
    float4 s3 = *(const float4*)&Pw[tt_r][c0 + 12];
    float r = ((s0.x + s0.y) + (s0.z + s0.w))
            + ((s1.x + s1.y) + (s1.z + s1.w))
            + ((s2.x + s2.y) + (s2.z + s2.w))
            + ((s3.x + s3.y) + (s3.z + s3.w));
    r += __shfl_xor(r, 1, 64);
    r += __shfl_xor(r, 2, 64);
    if ((lane & 3) == 0)
      yp[(size_t)(t0 + tt_r) << 10] = (_Float16)(fmaf(xvl, dpv, r) * zs);

    // ---- stage next BC buffer, then sync ----
    *(float4*)&BC[1 - p][0][ct][cs] = nb;
    *(float4*)&BC[1 - p][1][ct][cs] = nc;
    __syncthreads();
  }
}

// out[b,c] = h[b,L-1,:] . fc_w[c,:] + fc_b[c]; h is fp32 [4096][512]
__global__ void head_kernel(const float* __restrict__ h,
                            const float* __restrict__ fc_w,
                            const float* __restrict__ fc_b,
                            float* __restrict__ out)
{
  int bc = blockIdx.x;            // 0..11
  int b = bc / 3, c = bc % 3;
  int lane = threadIdx.x;
  const float* hr = h + (size_t)(b*1024 + 1023) * 512;
  const float* wr = fc_w + c*512;
  float s = 0.f;
  #pragma unroll
  for (int i = 0; i < 8; ++i) s = fmaf(hr[lane + i*64], wr[lane + i*64], s);
  #pragma unroll
  for (int o = 32; o > 0; o >>= 1) s += __shfl_xor(s, o, 64);
  if (lane == 0) out[b*3 + c] = s + fc_b[c];
}

extern "C" void kernel_launch(void* const* d_in, const int* in_sizes, int n_in,
                              void* d_out, int out_size, void* d_ws, size_t ws_size,
                              hipStream_t stream)
{
  const float* x        = (const float*)d_in[0];
  const float* exp_w    = (const float*)d_in[1];
  const float* exp_b    = (const float*)d_in[2];
  const float* in_w     = (const float*)d_in[3];
  const float* conv_w   = (const float*)d_in[4];
  const float* conv_b   = (const float*)d_in[5];
  const float* xproj_w  = (const float*)d_in[6];
  const float* dtproj_w = (const float*)d_in[7];
  const float* dtproj_b = (const float*)d_in[8];
  const float* A_log    = (const float*)d_in[9];
  const float* Dp       = (const float*)d_in[10];
  const float* out_w    = (const float*)d_in[11];
  const float* fc_w     = (const float*)d_in[12];
  const float* fc_b     = (const float*)d_in[13];
  float* out = (float*)d_out;

  // Workspace layout (byte offsets), 67 MB total (<= 74.8 MB proven in R1).
  // 8..24 MB region reused: xcpre (in_proj -> conv_t) -> dtT (dtproj -> scan).
  // y16 has its own region (written by scan WHILE dtT is read).
  char* ws = (char*)d_ws;
  float*    hf    = (float*)   (ws);                          //  8 MB [4096][512] fp32
  float*    xcpre = (float*)   (ws + ((size_t)8  << 20));     // 16 MB [4096][1024]
  float*    dtT   = (float*)   (ws + ((size_t)8  << 20));     // 16 MB [1024][4096] (reuse)
  float*    xcT   = (float*)   (ws + ((size_t)24 << 20));     // 16 MB [1024][4096]
  _Float16* zsT   = (_Float16*)(ws + ((size_t)40 << 20));     //  8 MB [1024][4096]
  float*    dbc   = (float*)   (ws + ((size_t)48 << 20));     //  2.6 MB [4096][160]
  _Float16* xc16  = (_Float16*)(ws + ((size_t)51 << 20));     //  8 MB [4096][1024]
  _Float16* y16   = (_Float16*)(ws + ((size_t)59 << 20));     //  8 MB [4096][1024]

  dim3 blk(256);

  // expand: hf = x @ exp_w^T + exp_b   [4096,512] K=128, fp32 out. 512 blocks.
  gemm_mfma<0,64,0,0,0,0><<<dim3(8,64), blk, 0, stream>>>(x, 128, exp_w, exp_b,
                                                          hf, 512, 512, 128, 1.f, nullptr);

  for (int l = 0; l < 2; ++l) {
    const float* inw = in_w + (size_t)l * 2048 * 512;
    // fused in_proj: xcpre [4096][1024] f32 + zsT [1024][4096] silu f16.
    // N=2048 K=512. 1024 blocks (4/CU).
    gemm_mfma<0,128,0,0,0,1><<<dim3(16,64), blk, 0, stream>>>(hf, 512, inw, nullptr,
                                                              xcpre, 1024, 2048, 512, 1.f,
                                                              zsT);
    // conv + silu -> xcT (fp32, scan) + xc16 (f16, xproj A)
    conv_t_kernel<<<1024, blk, 0, stream>>>(xcpre, conv_w + l*2048, conv_b + l*1024,
                                            xcT, xc16);
    // xproj: dbc = xc @ xproj_w^T   [4096,160] K=1024. 192 blocks.
    gemm_mfma<1,64,0,0,0,0><<<dim3(3,64), blk, 0, stream>>>(xc16, 1024,
                                                            xproj_w + (size_t)l*160*1024,
                                                            nullptr, dbc, 160, 160, 1024,
                                                            1.f, nullptr);
    // dtproj (transposed + softplus): dtT [1024][4096], A=dbc lda=160, K=32.
    gemm_mfma<0,64,1,1,0,0><<<dim3(16,64), blk, 0, stream>>>(dbc, 160,
                                                             dtproj_w + (size_t)l*1024*32,
                                                             dtproj_b + l*1024,
                                                             dtT, 4096, 1024, 32, 1.f,
                                                             nullptr);
    // selective scan; y16 = f16((scan + x*Dp)*silu(z) * 2^14) [bl][d]
    scan_kernel<<<1024, blk, 0, stream>>>(dtT, xcT, zsT, dbc,
                                          A_log + (size_t)l*65536, Dp + l*1024, y16);
    // out_proj: hf = (y16 @ out_w^T) * 2^-14   [4096,512] K=1024. 512 blocks.
    gemm_mfma<1,64,0,0,0,0><<<dim3(8,64), blk, 0, stream>>>(y16, 1024,
                                                            out_w + (size_t)l*512*1024,
                                                            nullptr, hf, 512, 512, 1024,
                                                            1.f / Y_SCALE, nullptr);
  }

  head_kernel<<<12, 64, 0, stream>>>(hf, fc_w, fc_b, out);
}

// Round 13
// 505.049 us; speedup vs baseline: 1.7154x; 1.0035x over previous
//
#include <hip/hip_runtime.h>
#include <math.h>

// Problem constants: B=4, L=1024, D_IN=128, D_MODEL=512, N_LAYERS=2,
// N_CLASSES=3, D_INNER=1024, D_STATE=64, D_CONV=2, DT_RANK=32, BL=4096.
//
// Precision plan (values shrink ~1000x per layer; final output ~3e-8):
//  - residual h kept fp32 end-to-end (layer-2 h ~3e-8 is f16-subnormal).
//  - y scaled by 2^14 at f16 conversion (in the scan store); out_proj
//    epilogue multiplies by 2^-14 (exact powers of two).
//
// R13: in_proj z-half and dtproj epilogues were 64-line scatter stores
// (8-16B at 8-16KB stride per lane). Both now transpose through LDS and
// store row-contiguous 16B chunks (the conv_t pattern, fused).

using half8  = __attribute__((ext_vector_type(8))) _Float16;
using half4v = __attribute__((ext_vector_type(4))) _Float16;
using f32x4  = __attribute__((ext_vector_type(4))) float;

#define Y_SCALE 16384.0f   // 2^14

__device__ __forceinline__ float silu_f(float v) {
  return v / (1.f + __expf(-v));
}

__device__ __forceinline__ half8 pack_f16(float4 a, float4 b) {
  half8 r;
  r[0] = (_Float16)a.x; r[1] = (_Float16)a.y; r[2] = (_Float16)a.z; r[3] = (_Float16)a.w;
  r[4] = (_Float16)b.x; r[5] = (_Float16)b.y; r[6] = (_Float16)b.z; r[7] = (_Float16)b.w;
  return r;
}

// ---------------------------------------------------------------------------
// f16 MFMA GEMM, 64 x BN tile. Block 256 thr = 4 waves; wave-tile 32 x (BN/2),
// MI=2 m-frags. BK=32 (one mfma_16x16x32 k-step).
// A: [M][K] row-major, fp32 (AF16=0) or f16 (AF16=1), leading dim lda.
// W: [N][K] fp32 row-major (converted to f16 in staging).
// MODE 0: C per TC/ACT/OF16 (TC=0 -> [M][N]; TC=1 -> [N][M] direct).
// MODE 1 (fused in_proj, N=2048, BN=128): n0<1024 -> Cv fp32 [M][1024];
//        n0>=1024 -> Cv2 f16 silu [n-1024][4096] via LDS transpose (R13).
// MODE 3 (dtproj, BN=64): softplus(acc+bias) -> Cv fp32 [N][4096] via LDS
//        transpose (R13), coalesced row stores.
// MFMA layouts (m89/m120-verified): A-frag A[m=lane&15][k=q*8+j],
// B-frag B[k=q*8+j][n=lane&15], D: col(n)=lane&15, row(m)=q*4+r.
// ---------------------------------------------------------------------------
template<int AF16, int BN, int TC, int ACT, int OF16, int MODE>
__global__ __launch_bounds__(256)
void gemm_mfma(const void* __restrict__ Av, int lda,
               const float* __restrict__ W,
               const float* __restrict__ bias,
               void* __restrict__ Cv, int ldc,
               int N, int K, float oscale,
               void* __restrict__ Cv2)
{
  constexpr int NF = BN / 32;            // n-frags per wave
  __shared__ _Float16 As[64 * 40];       // [m][k], row stride 40 f16 (80 B)
  __shared__ _Float16 Ws[BN * 40];       // [n][k]
  __shared__ _Float16 Tz[(MODE == 1) ? 128 * 72 : 8];   // z-half transpose
  __shared__ float    Td[(MODE == 3) ? 64 * 68  : 2];   // dtproj transpose
  const int tid  = threadIdx.x;
  const int lane = tid & 63;
  const int wid  = tid >> 6;
  const int wm   = wid & 1, wn = wid >> 1;   // wave-tile: 32 m x BN/2 n
  const int m0   = blockIdx.y * 64;
  const int n0   = blockIdx.x * BN;
  const int q    = lane >> 4, l16 = lane & 15;

  // A staging: 64 rows, 4 threads/row, 8 halfs each
  const int ar  = tid >> 2;
  const int akq = (tid & 3) * 8;
  // W staging: BN=128: 2 thr/row x 16 halfs; BN=64: 4 thr/row x 8 halfs
  const int wr  = (BN == 128) ? (tid >> 1) : (tid >> 2);
  const int wkq = (BN == 128) ? ((tid & 1) * 16) : ((tid & 3) * 8);
  const int wrow = n0 + wr;
  const bool wv  = (wrow < N);

  const float*    Af = (const float*)Av;
  const _Float16* Ah = (const _Float16*)Av;
  const float*    Wp = W + (size_t)wrow * K;
  const size_t aoff = (size_t)(m0 + ar) * lda + akq;

  float4 raf[2]; half8 rah; float4 rwf[4];
  const float4 zf4 = make_float4(0.f, 0.f, 0.f, 0.f);

  // initial loads (k0 = 0)
  if (AF16) {
    rah = *(const half8*)(Ah + aoff);
  } else {
    const float* p = Af + aoff;
    raf[0] = *(const float4*)p; raf[1] = *(const float4*)(p + 4);
  }
  if (BN == 128) {
    if (wv) {
      const float* p = Wp + wkq;
      rwf[0] = *(const float4*)p;       rwf[1] = *(const float4*)(p + 4);
      rwf[2] = *(const float4*)(p + 8); rwf[3] = *(const float4*)(p + 12);
    } else { rwf[0] = rwf[1] = rwf[2] = rwf[3] = zf4; }
  } else {
    if (wv) {
      const float* p = Wp + wkq;
      rwf[0] = *(const float4*)p; rwf[1] = *(const float4*)(p + 4);
    } else { rwf[0] = rwf[1] = zf4; }
  }

  f32x4 acc[2][NF];
  #pragma unroll
  for (int mi = 0; mi < 2; ++mi)
    #pragma unroll
    for (int ni = 0; ni < NF; ++ni)
      acc[mi][ni] = (f32x4){0.f, 0.f, 0.f, 0.f};

  for (int k0 = 0; k0 < K; k0 += 32) {
    if (k0) __syncthreads();
    if (AF16) *(half8*)&As[ar * 40 + akq] = rah;
    else      *(half8*)&As[ar * 40 + akq] = pack_f16(raf[0], raf[1]);
    if (BN == 128) {
      *(half8*)&Ws[wr * 40 + wkq]     = pack_f16(rwf[0], rwf[1]);
      *(half8*)&Ws[wr * 40 + wkq + 8] = pack_f16(rwf[2], rwf[3]);
    } else {
      *(half8*)&Ws[wr * 40 + wkq]     = pack_f16(rwf[0], rwf[1]);
    }
    __syncthreads();

    if (k0 + 32 < K) {            // prefetch next chunk
      const int kn = k0 + 32;
      if (AF16) {
        rah = *(const half8*)(Ah + aoff + kn);
      } else {
        const float* p = Af + aoff + kn;
        raf[0] = *(const float4*)p; raf[1] = *(const float4*)(p + 4);
      }
      if (BN == 128) {
        if (wv) {
          const float* p = Wp + kn + wkq;
          rwf[0] = *(const float4*)p;       rwf[1] = *(const float4*)(p + 4);
          rwf[2] = *(const float4*)(p + 8); rwf[3] = *(const float4*)(p + 12);
        }
      } else {
        if (wv) {
          const float* p = Wp + kn + wkq;
          rwf[0] = *(const float4*)p; rwf[1] = *(const float4*)(p + 4);
        }
      }
    }

    half8 af[2], wf[NF];
    #pragma unroll
    for (int mi = 0; mi < 2; ++mi)
      af[mi] = *(const half8*)&As[(wm * 32 + mi * 16 + l16) * 40 + q * 8];
    #pragma unroll
    for (int ni = 0; ni < NF; ++ni)
      wf[ni] = *(const half8*)&Ws[(wn * (BN / 2) + ni * 16 + l16) * 40 + q * 8];
    #pragma unroll
    for (int mi = 0; mi < 2; ++mi)
      #pragma unroll
      for (int ni = 0; ni < NF; ++ni)
        acc[mi][ni] = __builtin_amdgcn_mfma_f32_16x16x32_f16(af[mi], wf[ni],
                                                             acc[mi][ni], 0, 0, 0);
  }

  float*    Cf = (float*)Cv;
  _Float16* Ch = (_Float16*)Cv;

  if (MODE == 1) {
    if (n0 < 1024) {
      // xc half: fp32 [M][1024], fragment-row stores (64B runs, acceptable)
      #pragma unroll
      for (int ni = 0; ni < NF; ++ni) {
        const int n = n0 + wn * (BN / 2) + ni * 16 + l16;
        #pragma unroll
        for (int mi = 0; mi < 2; ++mi) {
          const int mb = m0 + wm * 32 + mi * 16 + q * 4;
          #pragma unroll
          for (int r = 0; r < 4; ++r)
            Cf[(size_t)(mb + r) * 1024 + n] = acc[mi][ni][r];
        }
      }
    } else {
      // z half: silu -> f16, LDS transpose, coalesced 16B row stores (R13)
      _Float16* Ch2 = (_Float16*)Cv2;
      __syncthreads();                       // protect Ws reuse window
      #pragma unroll
      for (int ni = 0; ni < NF; ++ni) {
        const int nnl = wn * (BN / 2) + ni * 16 + l16;   // 0..127 local
        #pragma unroll
        for (int mi = 0; mi < 2; ++mi) {
          const int mbl = wm * 32 + mi * 16 + q * 4;     // 0..63 local
          half4v h4;
          #pragma unroll
          for (int r = 0; r < 4; ++r) h4[r] = (_Float16)silu_f(acc[mi][ni][r]);
          *(half4v*)&Tz[nnl * 72 + mbl] = h4;
        }
      }
      __syncthreads();
      const int sr = tid >> 3;          // 0..31
      const int sc = (tid & 7) * 8;     // halfs 0..56
      #pragma unroll
      for (int rd = 0; rd < 4; ++rd) {
        const int row = rd * 32 + sr;
        half8 v = *(const half8*)&Tz[row * 72 + sc];
        *(half8*)&Ch2[(size_t)(n0 - 1024 + row) * 4096 + m0 + sc] = v;
      }
    }
    return;
  }

  if (MODE == 3) {
    // dtproj: softplus(acc*oscale + bias) -> fp32 [N][4096] via LDS transpose
    __syncthreads();
    #pragma unroll
    for (int ni = 0; ni < NF; ++ni) {
      const int nnl = wn * (BN / 2) + ni * 16 + l16;     // 0..63 local
      const float bv = (bias != nullptr) ? bias[n0 + nnl] : 0.f;
      #pragma unroll
      for (int mi = 0; mi < 2; ++mi) {
        const int mbl = wm * 32 + mi * 16 + q * 4;       // 0..63 local
        float o[4];
        #pragma unroll
        for (int r = 0; r < 4; ++r) {
          float v = acc[mi][ni][r] * oscale + bv;
          o[r] = (v > 20.f) ? v : log1pf(__expf(v));     // softplus
        }
        *(float4*)&Td[nnl * 68 + mbl] = make_float4(o[0], o[1], o[2], o[3]);
      }
    }
    __syncthreads();
    const int sr = tid >> 4;            // 0..15
    const int sc = (tid & 15) * 4;      // floats 0..60
    #pragma unroll
    for (int rd = 0; rd < 4; ++rd) {
      const int row = rd * 16 + sr;
      float4 v = *(const float4*)&Td[row * 68 + sc];
      *(float4*)&Cf[(size_t)(n0 + row) * 4096 + m0 + sc] = v;
    }
    return;
  }

  // MODE 0 epilogue
  #pragma unroll
  for (int ni = 0; ni < NF; ++ni) {
    const int n = n0 + wn * (BN / 2) + ni * 16 + l16;
    if (n < N) {
      const float bv = (bias != nullptr) ? bias[n] : 0.f;
      #pragma unroll
      for (int mi = 0; mi < 2; ++mi) {
        const int mb = m0 + wm * 32 + mi * 16 + q * 4;
        float o[4];
        #pragma unroll
        for (int r = 0; r < 4; ++r) {
          float v = acc[mi][ni][r] * oscale + bv;
          if (ACT == 1) v = (v > 20.f) ? v : log1pf(__expf(v));
          if (ACT == 2) v = silu_f(v);
          o[r] = v;
        }
        if (TC == 0) {
          #pragma unroll
          for (int r = 0; r < 4; ++r) {
            size_t off = (size_t)(mb + r) * ldc + n;
            if (OF16) Ch[off] = (_Float16)o[r];
            else      Cf[off] = o[r];
          }
        } else {
          size_t off = (size_t)n * ldc + mb;
          if (OF16) {
            half4v h4; h4[0]=(_Float16)o[0]; h4[1]=(_Float16)o[1];
                       h4[2]=(_Float16)o[2]; h4[3]=(_Float16)o[3];
            *(half4v*)&Ch[off] = h4;
          } else {
            *(float4*)&Cf[off] = make_float4(o[0], o[1], o[2], o[3]);
          }
        }
      }
    }
  }
}

// ---------------------------------------------------------------------------
// Depthwise causal conv (D_CONV=2) + silu, 64x64 LDS transpose.
// in : xcp [4096 bl][1024 d] fp32
// out: xcT [1024 d][4096 bl] fp32 (scan input)  +  xcf [4096 bl][1024 d] f16
// ---------------------------------------------------------------------------
__global__ void conv_t_kernel(const float* __restrict__ xcp,
                              const float* __restrict__ cw,   // [1024][2]
                              const float* __restrict__ cb,   // [1024]
                              float* __restrict__ xcT,
                              _Float16* __restrict__ xcf)
{
  __shared__ float tile[64][65];
  const int blk = blockIdx.x;            // b*256 + tt*16 + dd
  const int b  = blk >> 8;
  const int tt = (blk >> 4) & 15;
  const int dd = blk & 15;
  const int t0 = tt * 64, d0 = dd * 64;
  const int tid = threadIdx.x;

  #pragma unroll
  for (int i = 0; i < 16; ++i) {
    int idx = i * 256 + tid;
    int t = idx >> 6, d = idx & 63;
    int gt = t0 + t;
    size_t rcur = ((size_t)(b * 1024 + gt) << 10) + d0 + d;
    float cur  = xcp[rcur];
    float prev = (gt > 0) ? xcp[rcur - 1024] : 0.f;
    float v = fmaf(prev, cw[(d0+d)*2], fmaf(cur, cw[(d0+d)*2 + 1], cb[d0+d]));
    float sv = silu_f(v);
    tile[t][d] = sv;
    xcf[rcur] = (_Float16)sv;
  }
  __syncthreads();
  #pragma unroll
  for (int i = 0; i < 16; ++i) {
    int idx = i * 256 + tid;
    int d = idx >> 6, t = idx & 63;
    xcT[((size_t)(d0 + d) << 12) + b * 1024 + t0 + t] = tile[t][d];
  }
}

// ---------------------------------------------------------------------------
// Selective scan, time-major. One wave per (b,d), lane = s (D_STATE=64).
// R9 core + R12 XCD swizzle + direct f16 y store (proven 118 us).
// ---------------------------------------------------------------------------
__global__ __launch_bounds__(256, 4)
void scan_kernel(const float* __restrict__ dtT,     // [1024][4096]
                 const float* __restrict__ xcT,     // [1024][4096]
                 const _Float16* __restrict__ zsT,  // [1024][4096], silu(z), f16
                 const float* __restrict__ dbc,     // [B][1024][160]; B@+32, C@+96
                 const float* __restrict__ A_log,   // [1024][64]
                 const float* __restrict__ Dp,      // [1024]
                 _Float16* __restrict__ y16)        // [4096 bl][1024 d], y*2^14
{
  __shared__ float P[4][16][68];       // per-wave reduction tile
  __shared__ float BC[2][2][16][64];   // [buf][B/C][t][s], block-shared
  const int tid  = threadIdx.x;
  const int lane = tid & 63;
  const int wrp  = tid >> 6;
  const int rb   = blockIdx.x;
  const int bswz = ((rb & 7) << 7) | (rb >> 3);          // XCD swizzle
  const int wid  = __builtin_amdgcn_readfirstlane(bswz * 4 + wrp);
  const int b = wid >> 10;             // block-uniform
  const int d = wid & 1023;
  float (*Pw)[68] = P[wrp];

  const float a   = -__expf(A_log[d*64 + lane]);
  const float dpv = Dp[d];
  const size_t row = ((size_t)d << 12) + b * 1024;
  const float*    dtp = dtT + row;
  const float*    xp  = xcT + row;
  const _Float16* zsp = zsT + row;
  _Float16*       yp  = y16 + ((size_t)b << 20) + d;     // + t*1024

  const int ct = tid >> 4;             // 0..15
  const int cs = (tid & 15) * 4;       // 0..60
  const float* bcbase = dbc + (size_t)b * 163840 + (size_t)ct * 160 + cs;

  const int tt_r = lane >> 2;
  const int c0   = (lane & 3) << 4;

  {
    *(float4*)&BC[0][0][ct][cs] = *(const float4*)(bcbase + 32);
    *(float4*)&BC[0][1][ct][cs] = *(const float4*)(bcbase + 96);
  }
  __syncthreads();

  float h = 0.f;
  for (int t0 = 0; t0 < 1024; t0 += 16) {
    const int p = (t0 >> 4) & 1;
    const int tn = (t0 + 16 < 1024) ? (t0 + 16) : t0;
    float4 nb = *(const float4*)(bcbase + (size_t)tn * 160 + 32);
    float4 nc = *(const float4*)(bcbase + (size_t)tn * 160 + 96);

    float4 dq[4], xq[4];
    #pragma unroll
    for (int i = 0; i < 4; ++i) {
      dq[i] = *(const float4*)(dtp + t0 + i*4);
      xq[i] = *(const float4*)(xp  + t0 + i*4);
    }
    float zs  = (float)zsp[t0 + tt_r] * Y_SCALE;   // exact 2^14 fold
    float xvl = xp[t0 + tt_r];
    const float* dtv = reinterpret_cast<const float*>(dq);
    const float* xv  = reinterpret_cast<const float*>(xq);

    float dA[16], ub[16], Cv[16];
    #pragma unroll
    for (int tt = 0; tt < 16; ++tt) {
      float Bv = BC[p][0][tt][lane];
      Cv[tt]   = BC[p][1][tt][lane];
      dA[tt] = __expf(dtv[tt] * a);
      ub[tt] = dtv[tt] * xv[tt] * Bv;
    }
    #pragma unroll
    for (int tt = 0; tt < 16; ++tt) {
      h = fmaf(h, dA[tt], ub[tt]);
      Pw[tt][lane] = h * Cv[tt];
    }

    float4 s0 = *(const float4*)&Pw[tt_r][c0];
    float4 s1 = *(const float4*)&Pw[tt_r][c0 + 4];
    float4 s2 = *(const float4*)&Pw[tt_r][c0 + 8];
    float4 s3 = *(const float4*)&Pw[tt_r][c0 + 12];
    float r = ((s0.x + s0.y) + (s0.z + s0.w))
            + ((s1.x + s1.y) + (s1.z + s1.w))
            + ((s2.x + s2.y) + (s2.z + s2.w))
            + ((s3.x + s3.y) + (s3.z + s3.w));
    r += __shfl_xor(r, 1, 64);
    r += __shfl_xor(r, 2, 64);
    if ((lane & 3) == 0)
      yp[(size_t)(t0 + tt_r) << 10] = (_Float16)(fmaf(xvl, dpv, r) * zs);

    *(float4*)&BC[1 - p][0][ct][cs] = nb;
    *(float4*)&BC[1 - p][1][ct][cs] = nc;
    __syncthreads();
  }
}

// out[b,c] = h[b,L-1,:] . fc_w[c,:] + fc_b[c]; h is fp32 [4096][512]
__global__ void head_kernel(const float* __restrict__ h,
                            const float* __restrict__ fc_w,
                            const float* __restrict__ fc_b,
                            float* __restrict__ out)
{
  int bc = blockIdx.x;            // 0..11
  int b = bc / 3, c = bc % 3;
  int lane = threadIdx.x;
  const float* hr = h + (size_t)(b*1024 + 1023) * 512;
  const float* wr = fc_w + c*512;
  float s = 0.f;
  #pragma unroll
  for (int i = 0; i < 8; ++i) s = fmaf(hr[lane + i*64], wr[lane + i*64], s);
  #pragma unroll
  for (int o = 32; o > 0; o >>= 1) s += __shfl_xor(s, o, 64);
  if (lane == 0) out[b*3 + c] = s + fc_b[c];
}

extern "C" void kernel_launch(void* const* d_in, const int* in_sizes, int n_in,
                              void* d_out, int out_size, void* d_ws, size_t ws_size,
                              hipStream_t stream)
{
  const float* x        = (const float*)d_in[0];
  const float* exp_w    = (const float*)d_in[1];
  const float* exp_b    = (const float*)d_in[2];
  const float* in_w     = (const float*)d_in[3];
  const float* conv_w   = (const float*)d_in[4];
  const float* conv_b   = (const float*)d_in[5];
  const float* xproj_w  = (const float*)d_in[6];
  const float* dtproj_w = (const float*)d_in[7];
  const float* dtproj_b = (const float*)d_in[8];
  const float* A_log    = (const float*)d_in[9];
  const float* Dp       = (const float*)d_in[10];
  const float* out_w    = (const float*)d_in[11];
  const float* fc_w     = (const float*)d_in[12];
  const float* fc_b     = (const float*)d_in[13];
  float* out = (float*)d_out;

  // Workspace layout (byte offsets), 67 MB total.
  char* ws = (char*)d_ws;
  float*    hf    = (float*)   (ws);                          //  8 MB [4096][512] fp32
  float*    xcpre = (float*)   (ws + ((size_t)8  << 20));     // 16 MB [4096][1024]
  float*    dtT   = (float*)   (ws + ((size_t)8  << 20));     // 16 MB [1024][4096] (reuse)
  float*    xcT   = (float*)   (ws + ((size_t)24 << 20));     // 16 MB [1024][4096]
  _Float16* zsT   = (_Float16*)(ws + ((size_t)40 << 20));     //  8 MB [1024][4096]
  float*    dbc   = (float*)   (ws + ((size_t)48 << 20));     //  2.6 MB [4096][160]
  _Float16* xc16  = (_Float16*)(ws + ((size_t)51 << 20));     //  8 MB [4096][1024]
  _Float16* y16   = (_Float16*)(ws + ((size_t)59 << 20));     //  8 MB [4096][1024]

  dim3 blk(256);

  // expand: hf = x @ exp_w^T + exp_b   [4096,512] K=128, fp32 out. 512 blocks.
  gemm_mfma<0,64,0,0,0,0><<<dim3(8,64), blk, 0, stream>>>(x, 128, exp_w, exp_b,
                                                          hf, 512, 512, 128, 1.f, nullptr);

  for (int l = 0; l < 2; ++l) {
    const float* inw = in_w + (size_t)l * 2048 * 512;
    // fused in_proj: xcpre [4096][1024] f32 + zsT [1024][4096] silu f16
    // (z-half via LDS transpose). N=2048 K=512. 1024 blocks.
    gemm_mfma<0,128,0,0,0,1><<<dim3(16,64), blk, 0, stream>>>(hf, 512, inw, nullptr,
                                                              xcpre, 1024, 2048, 512, 1.f,
                                                              zsT);
    // conv + silu -> xcT (fp32, scan) + xc16 (f16, xproj A)
    conv_t_kernel<<<1024, blk, 0, stream>>>(xcpre, conv_w + l*2048, conv_b + l*1024,
                                            xcT, xc16);
    // xproj: dbc = xc @ xproj_w^T   [4096,160] K=1024. 192 blocks.
    gemm_mfma<1,64,0,0,0,0><<<dim3(3,64), blk, 0, stream>>>(xc16, 1024,
                                                            xproj_w + (size_t)l*160*1024,
                                                            nullptr, dbc, 160, 160, 1024,
                                                            1.f, nullptr);
    // dtproj (MODE 3): dtT [1024][4096] softplus, LDS-transposed stores.
    gemm_mfma<0,64,0,1,0,3><<<dim3(16,64), blk, 0, stream>>>(dbc, 160,
                                                             dtproj_w + (size_t)l*1024*32,
                                                             dtproj_b + l*1024,
                                                             dtT, 4096, 1024, 32, 1.f,
                                                             nullptr);
    // selective scan; y16 = f16((scan + x*Dp)*silu(z) * 2^14) [bl][d]
    scan_kernel<<<1024, blk, 0, stream>>>(dtT, xcT, zsT, dbc,
                                          A_log + (size_t)l*65536, Dp + l*1024, y16);
    // out_proj: hf = (y16 @ out_w^T) * 2^-14   [4096,512] K=1024. 512 blocks.
    gemm_mfma<1,64,0,0,0,0><<<dim3(8,64), blk, 0, stream>>>(y16, 1024,
                                                            out_w + (size_t)l*512*1024,
                                                            nullptr, hf, 512, 512, 1024,
                                                            1.f / Y_SCALE, nullptr);
  }

  head_kernel<<<12, 64, 0, stream>>>(hf, fc_w, fc_b, out);
}

// Round 14
// 461.800 us; speedup vs baseline: 1.8760x; 1.0937x over previous
//
#include <hip/hip_runtime.h>
#include <math.h>

// Problem constants: B=4, L=1024, D_IN=128, D_MODEL=512, N_LAYERS=2,
// N_CLASSES=3, D_INNER=1024, D_STATE=64, D_CONV=2, DT_RANK=32, BL=4096.
//
// Precision plan: all GEMM operands f16 (conversions hoisted upstream,
// bit-identical to the old staging-time conversions). Residual h: layer-1
// h stored f16 scaled by 2^8 (exact), layer-2 h fp32 for the head (h2~3e-8
// is f16-subnormal). y scaled by 2^14 at the scan store; out_proj epilogue
// rescales. All scales exact powers of two.

using half8  = __attribute__((ext_vector_type(8))) _Float16;
using half4v = __attribute__((ext_vector_type(4))) _Float16;
using f32x4  = __attribute__((ext_vector_type(4))) float;

#define Y_SCALE 16384.0f   // 2^14
#define H1_SCALE 256.0f    // 2^8

__device__ __forceinline__ float silu_f(float v) {
  return v / (1.f + __expf(-v));
}

// ---------------------------------------------------------------------------
// One-shot fp32 -> f16 conversion of all weights + x into the w16 pool.
// Element offsets (all range boundaries are multiples of 1024 = one block's
// span, so the source select is block-uniform):
//   exp_w 0..65536 | in_w ..2162688 | xproj_w ..2490368 | dtproj_w ..2555904
//   | out_w ..3604480 | x ..4128768
// ---------------------------------------------------------------------------
__global__ void wcvt_kernel(const float* __restrict__ exp_w,
                            const float* __restrict__ in_w,
                            const float* __restrict__ xproj_w,
                            const float* __restrict__ dtproj_w,
                            const float* __restrict__ out_w,
                            const float* __restrict__ x,
                            _Float16* __restrict__ w16)
{
  size_t gi = ((size_t)blockIdx.x * 256 + threadIdx.x) * 4;
  const float* src; size_t off;
  if      (gi < 65536)   { src = exp_w;    off = gi; }
  else if (gi < 2162688) { src = in_w;     off = gi - 65536; }
  else if (gi < 2490368) { src = xproj_w;  off = gi - 2162688; }
  else if (gi < 2555904) { src = dtproj_w; off = gi - 2490368; }
  else if (gi < 3604480) { src = out_w;    off = gi - 2555904; }
  else                   { src = x;        off = gi - 3604480; }
  float4 v = *(const float4*)(src + off);
  half4v h;
  h[0] = (_Float16)v.x; h[1] = (_Float16)v.y;
  h[2] = (_Float16)v.z; h[3] = (_Float16)v.w;
  *(half4v*)(w16 + gi) = h;
}

// ---------------------------------------------------------------------------
// f16 MFMA GEMM, 64 x BN tile. Block 256 thr = 4 waves; wave-tile 32 x (BN/2),
// MI=2 m-frags. BK=32. A and W are BOTH f16 now (R14): staging is pure
// half8 load -> ds_write, no conversions, half the W bytes.
// MODE 0: C = oscale*acc + bias, ACT, OF16 -> [M][N] ldc.
// MODE 1 (fused in_proj, N=2048, BN=128): n0<1024 -> Cv fp32 [M][1024]
//        = acc*oscale; n0>=1024 -> Cv2 f16 silu(acc*oscale) [n-1024][4096]
//        via LDS transpose.
// MODE 2 (xproj, N=160): n<32 -> Cv2 dtr16 f16 [M][32]; 32<=n<160 -> Cv
//        dbc fp32 [M][160].
// MODE 3 (dtproj): softplus(acc*oscale+bias) -> Cv fp32 [N][4096] via LDS
//        transpose, coalesced row stores.
// MFMA layouts (m89/m120-verified): A-frag A[m=lane&15][k=q*8+j],
// B-frag B[k=q*8+j][n=lane&15], D: col(n)=lane&15, row(m)=q*4+r.
// ---------------------------------------------------------------------------
template<int BN, int ACT, int OF16, int MODE>
__global__ __launch_bounds__(256)
void gemm_mfma(const _Float16* __restrict__ A, int lda,
               const _Float16* __restrict__ W,
               const float* __restrict__ bias,
               void* __restrict__ Cv, int ldc,
               int N, int K, float oscale,
               void* __restrict__ Cv2)
{
  constexpr int NF = BN / 32;            // n-frags per wave
  __shared__ _Float16 As[64 * 40];       // [m][k], row stride 40 f16 (80 B)
  __shared__ _Float16 Ws[BN * 40];       // [n][k]
  __shared__ _Float16 Tz[(MODE == 1) ? 128 * 72 : 8];   // z-half transpose
  __shared__ float    Td[(MODE == 3) ? 64 * 68  : 2];   // dtproj transpose
  const int tid  = threadIdx.x;
  const int lane = tid & 63;
  const int wid  = tid >> 6;
  const int wm   = wid & 1, wn = wid >> 1;   // wave-tile: 32 m x BN/2 n
  const int m0   = blockIdx.y * 64;
  const int n0   = blockIdx.x * BN;
  const int q    = lane >> 4, l16 = lane & 15;

  // A staging: 64 rows, 4 threads/row, 8 halfs each
  const int ar  = tid >> 2;
  const int akq = (tid & 3) * 8;
  // W staging: BN=128: 2 thr/row x 16 halfs; BN=64: 4 thr/row x 8 halfs
  const int wr  = (BN == 128) ? (tid >> 1) : (tid >> 2);
  const int wkq = (BN == 128) ? ((tid & 1) * 16) : ((tid & 3) * 8);
  const int wrow = n0 + wr;
  const bool wv  = (wrow < N);

  const _Float16* Wp = W + (size_t)wrow * K;
  const size_t aoff = (size_t)(m0 + ar) * lda + akq;

  half8 zh;
  #pragma unroll
  for (int i = 0; i < 8; ++i) zh[i] = (_Float16)0.f;

  // initial loads (k0 = 0)
  half8 rah = *(const half8*)(A + aoff);
  half8 rwh0 = zh, rwh1 = zh;
  if (wv) {
    rwh0 = *(const half8*)(Wp + wkq);
    if (BN == 128) rwh1 = *(const half8*)(Wp + wkq + 8);
  }

  f32x4 acc[2][NF];
  #pragma unroll
  for (int mi = 0; mi < 2; ++mi)
    #pragma unroll
    for (int ni = 0; ni < NF; ++ni)
      acc[mi][ni] = (f32x4){0.f, 0.f, 0.f, 0.f};

  for (int k0 = 0; k0 < K; k0 += 32) {
    if (k0) __syncthreads();
    *(half8*)&As[ar * 40 + akq] = rah;
    *(half8*)&Ws[wr * 40 + wkq] = rwh0;
    if (BN == 128) *(half8*)&Ws[wr * 40 + wkq + 8] = rwh1;
    __syncthreads();

    if (k0 + 32 < K) {            // prefetch next chunk
      const int kn = k0 + 32;
      rah = *(const half8*)(A + aoff + kn);
      if (wv) {
        rwh0 = *(const half8*)(Wp + kn + wkq);
        if (BN == 128) rwh1 = *(const half8*)(Wp + kn + wkq + 8);
      }
    }

    half8 af[2], wf[NF];
    #pragma unroll
    for (int mi = 0; mi < 2; ++mi)
      af[mi] = *(const half8*)&As[(wm * 32 + mi * 16 + l16) * 40 + q * 8];
    #pragma unroll
    for (int ni = 0; ni < NF; ++ni)
      wf[ni] = *(const half8*)&Ws[(wn * (BN / 2) + ni * 16 + l16) * 40 + q * 8];
    #pragma unroll
    for (int mi = 0; mi < 2; ++mi)
      #pragma unroll
      for (int ni = 0; ni < NF; ++ni)
        acc[mi][ni] = __builtin_amdgcn_mfma_f32_16x16x32_f16(af[mi], wf[ni],
                                                             acc[mi][ni], 0, 0, 0);
  }

  float*    Cf = (float*)Cv;
  _Float16* Ch = (_Float16*)Cv;

  if (MODE == 1) {
    if (n0 < 1024) {
      // xc half: fp32 [M][1024]
      #pragma unroll
      for (int ni = 0; ni < NF; ++ni) {
        const int n = n0 + wn * (BN / 2) + ni * 16 + l16;
        #pragma unroll
        for (int mi = 0; mi < 2; ++mi) {
          const int mb = m0 + wm * 32 + mi * 16 + q * 4;
          #pragma unroll
          for (int r = 0; r < 4; ++r)
            Cf[(size_t)(mb + r) * 1024 + n] = acc[mi][ni][r] * oscale;
        }
      }
    } else {
      // z half: silu -> f16, LDS transpose, coalesced 16B row stores
      _Float16* Ch2 = (_Float16*)Cv2;
      __syncthreads();
      #pragma unroll
      for (int ni = 0; ni < NF; ++ni) {
        const int nnl = wn * (BN / 2) + ni * 16 + l16;   // 0..127 local
        #pragma unroll
        for (int mi = 0; mi < 2; ++mi) {
          const int mbl = wm * 32 + mi * 16 + q * 4;     // 0..63 local
          half4v h4;
          #pragma unroll
          for (int r = 0; r < 4; ++r)
            h4[r] = (_Float16)silu_f(acc[mi][ni][r] * oscale);
          *(half4v*)&Tz[nnl * 72 + mbl] = h4;
        }
      }
      __syncthreads();
      const int sr = tid >> 3;          // 0..31
      const int sc = (tid & 7) * 8;     // halfs 0..56
      #pragma unroll
      for (int rd = 0; rd < 4; ++rd) {
        const int row = rd * 32 + sr;
        half8 v = *(const half8*)&Tz[row * 72 + sc];
        *(half8*)&Ch2[(size_t)(n0 - 1024 + row) * 4096 + m0 + sc] = v;
      }
    }
    return;
  }

  if (MODE == 2) {
    // xproj: n<32 -> dtr16 f16 [M][32]; 32<=n<160 -> dbc fp32 [M][160]
    _Float16* dtr = (_Float16*)Cv2;
    #pragma unroll
    for (int ni = 0; ni < NF; ++ni) {
      const int n = n0 + wn * (BN / 2) + ni * 16 + l16;
      #pragma unroll
      for (int mi = 0; mi < 2; ++mi) {
        const int mb = m0 + wm * 32 + mi * 16 + q * 4;
        if (n < 32) {
          #pragma unroll
          for (int r = 0; r < 4; ++r)
            dtr[(size_t)(mb + r) * 32 + n] = (_Float16)acc[mi][ni][r];
        } else if (n < 160) {
          #pragma unroll
          for (int r = 0; r < 4; ++r)
            Cf[(size_t)(mb + r) * 160 + n] = acc[mi][ni][r];
        }
      }
    }
    return;
  }

  if (MODE == 3) {
    // dtproj: softplus(acc*oscale + bias) -> fp32 [N][4096] via LDS transpose
    __syncthreads();
    #pragma unroll
    for (int ni = 0; ni < NF; ++ni) {
      const int nnl = wn * (BN / 2) + ni * 16 + l16;     // 0..63 local
      const float bv = (bias != nullptr) ? bias[n0 + nnl] : 0.f;
      #pragma unroll
      for (int mi = 0; mi < 2; ++mi) {
        const int mbl = wm * 32 + mi * 16 + q * 4;       // 0..63 local
        float o[4];
        #pragma unroll
        for (int r = 0; r < 4; ++r) {
          float v = acc[mi][ni][r] * oscale + bv;
          o[r] = (v > 20.f) ? v : log1pf(__expf(v));     // softplus
        }
        *(float4*)&Td[nnl * 68 + mbl] = make_float4(o[0], o[1], o[2], o[3]);
      }
    }
    __syncthreads();
    const int sr = tid >> 4;            // 0..15
    const int sc = (tid & 15) * 4;      // floats 0..60
    #pragma unroll
    for (int rd = 0; rd < 4; ++rd) {
      const int row = rd * 16 + sr;
      float4 v = *(const float4*)&Td[row * 68 + sc];
      *(float4*)&Cf[(size_t)(n0 + row) * 4096 + m0 + sc] = v;
    }
    return;
  }

  // MODE 0 epilogue
  #pragma unroll
  for (int ni = 0; ni < NF; ++ni) {
    const int n = n0 + wn * (BN / 2) + ni * 16 + l16;
    if (n < N) {
      const float bv = (bias != nullptr) ? bias[n] : 0.f;
      #pragma unroll
      for (int mi = 0; mi < 2; ++mi) {
        const int mb = m0 + wm * 32 + mi * 16 + q * 4;
        #pragma unroll
        for (int r = 0; r < 4; ++r) {
          float v = acc[mi][ni][r] * oscale + bv;
          if (ACT == 1) v = (v > 20.f) ? v : log1pf(__expf(v));
          if (ACT == 2) v = silu_f(v);
          size_t off = (size_t)(mb + r) * ldc + n;
          if (OF16) Ch[off] = (_Float16)v;
          else      Cf[off] = v;
        }
      }
    }
  }
}

// ---------------------------------------------------------------------------
// Depthwise causal conv (D_CONV=2) + silu, 64x64 LDS transpose.
// in : xcp [4096 bl][1024 d] fp32
// out: xcT [1024 d][4096 bl] fp32 (scan input)  +  xcf [4096 bl][1024 d] f16
// ---------------------------------------------------------------------------
__global__ void conv_t_kernel(const float* __restrict__ xcp,
                              const float* __restrict__ cw,   // [1024][2]
                              const float* __restrict__ cb,   // [1024]
                              float* __restrict__ xcT,
                              _Float16* __restrict__ xcf)
{
  __shared__ float tile[64][65];
  const int blk = blockIdx.x;            // b*256 + tt*16 + dd
  const int b  = blk >> 8;
  const int tt = (blk >> 4) & 15;
  const int dd = blk & 15;
  const int t0 = tt * 64, d0 = dd * 64;
  const int tid = threadIdx.x;

  #pragma unroll
  for (int i = 0; i < 16; ++i) {
    int idx = i * 256 + tid;
    int t = idx >> 6, d = idx & 63;
    int gt = t0 + t;
    size_t rcur = ((size_t)(b * 1024 + gt) << 10) + d0 + d;
    float cur  = xcp[rcur];
    float prev = (gt > 0) ? xcp[rcur - 1024] : 0.f;
    float v = fmaf(prev, cw[(d0+d)*2], fmaf(cur, cw[(d0+d)*2 + 1], cb[d0+d]));
    float sv = silu_f(v);
    tile[t][d] = sv;
    xcf[rcur] = (_Float16)sv;
  }
  __syncthreads();
  #pragma unroll
  for (int i = 0; i < 16; ++i) {
    int idx = i * 256 + tid;
    int d = idx >> 6, t = idx & 63;
    xcT[((size_t)(d0 + d) << 12) + b * 1024 + t0 + t] = tile[t][d];
  }
}

// ---------------------------------------------------------------------------
// Selective scan, time-major. One wave per (b,d), lane = s (D_STATE=64).
// R9 core + R12 XCD swizzle + direct f16 y store (proven 118 us). Unchanged.
// ---------------------------------------------------------------------------
__global__ __launch_bounds__(256, 4)
void scan_kernel(const float* __restrict__ dtT,     // [1024][4096]
                 const float* __restrict__ xcT,     // [1024][4096]
                 const _Float16* __restrict__ zsT,  // [1024][4096], silu(z), f16
                 const float* __restrict__ dbc,     // [B][1024][160]; B@+32, C@+96
                 const float* __restrict__ A_log,   // [1024][64]
                 const float* __restrict__ Dp,      // [1024]
                 _Float16* __restrict__ y16)        // [4096 bl][1024 d], y*2^14
{
  __shared__ float P[4][16][68];       // per-wave reduction tile
  __shared__ float BC[2][2][16][64];   // [buf][B/C][t][s], block-shared
  const int tid  = threadIdx.x;
  const int lane = tid & 63;
  const int wrp  = tid >> 6;
  const int rb   = blockIdx.x;
  const int bswz = ((rb & 7) << 7) | (rb >> 3);          // XCD swizzle
  const int wid  = __builtin_amdgcn_readfirstlane(bswz * 4 + wrp);
  const int b = wid >> 10;             // block-uniform
  const int d = wid & 1023;
  float (*Pw)[68] = P[wrp];

  const float a   = -__expf(A_log[d*64 + lane]);
  const float dpv = Dp[d];
  const size_t row = ((size_t)d << 12) + b * 1024;
  const float*    dtp = dtT + row;
  const float*    xp  = xcT + row;
  const _Float16* zsp = zsT + row;
  _Float16*       yp  = y16 + ((size_t)b << 20) + d;     // + t*1024

  const int ct = tid >> 4;             // 0..15
  const int cs = (tid & 15) * 4;       // 0..60
  const float* bcbase = dbc + (size_t)b * 163840 + (size_t)ct * 160 + cs;

  const int tt_r = lane >> 2;
  const int c0   = (lane & 3) << 4;

  {
    *(float4*)&BC[0][0][ct][cs] = *(const float4*)(bcbase + 32);
    *(float4*)&BC[0][1][ct][cs] = *(const float4*)(bcbase + 96);
  }
  __syncthreads();

  float h = 0.f;
  for (int t0 = 0; t0 < 1024; t0 += 16) {
    const int p = (t0 >> 4) & 1;
    const int tn = (t0 + 16 < 1024) ? (t0 + 16) : t0;
    float4 nb = *(const float4*)(bcbase + (size_t)tn * 160 + 32);
    float4 nc = *(const float4*)(bcbase + (size_t)tn * 160 + 96);

    float4 dq[4], xq[4];
    #pragma unroll
    for (int i = 0; i < 4; ++i) {
      dq[i] = *(const float4*)(dtp + t0 + i*4);
      xq[i] = *(const float4*)(xp  + t0 + i*4);
    }
    float zs  = (float)zsp[t0 + tt_r] * Y_SCALE;   // exact 2^14 fold
    float xvl = xp[t0 + tt_r];
    const float* dtv = reinterpret_cast<const float*>(dq);
    const float* xv  = reinterpret_cast<const float*>(xq);

    float dA[16], ub[16], Cv[16];
    #pragma unroll
    for (int tt = 0; tt < 16; ++tt) {
      float Bv = BC[p][0][tt][lane];
      Cv[tt]   = BC[p][1][tt][lane];
      dA[tt] = __expf(dtv[tt] * a);
      ub[tt] = dtv[tt] * xv[tt] * Bv;
    }
    #pragma unroll
    for (int tt = 0; tt < 16; ++tt) {
      h = fmaf(h, dA[tt], ub[tt]);
      Pw[tt][lane] = h * Cv[tt];
    }

    float4 s0 = *(const float4*)&Pw[tt_r][c0];
    float4 s1 = *(const float4*)&Pw[tt_r][c0 + 4];
    float4 s2 = *(const float4*)&Pw[tt_r][c0 + 8];
    float4 s3 = *(const float4*)&Pw[tt_r][c0 + 12];
    float r = ((s0.x + s0.y) + (s0.z + s0.w))
            + ((s1.x + s1.y) + (s1.z + s1.w))
            + ((s2.x + s2.y) + (s2.z + s2.w))
            + ((s3.x + s3.y) + (s3.z + s3.w));
    r += __shfl_xor(r, 1, 64);
    r += __shfl_xor(r, 2, 64);
    if ((lane & 3) == 0)
      yp[(size_t)(t0 + tt_r) << 10] = (_Float16)(fmaf(xvl, dpv, r) * zs);

    *(float4*)&BC[1 - p][0][ct][cs] = nb;
    *(float4*)&BC[1 - p][1][ct][cs] = nc;
    __syncthreads();
  }
}

// out[b,c] = h[b,L-1,:] . fc_w[c,:] + fc_b[c]; h is fp32 [4096][512]
__global__ void head_kernel(const float* __restrict__ h,
                            const float* __restrict__ fc_w,
                            const float* __restrict__ fc_b,
                            float* __restrict__ out)
{
  int bc = blockIdx.x;            // 0..11
  int b = bc / 3, c = bc % 3;
  int lane = threadIdx.x;
  const float* hr = h + (size_t)(b*1024 + 1023) * 512;
  const float* wr = fc_w + c*512;
  float s = 0.f;
  #pragma unroll
  for (int i = 0; i < 8; ++i) s = fmaf(hr[lane + i*64], wr[lane + i*64], s);
  #pragma unroll
  for (int o = 32; o > 0; o >>= 1) s += __shfl_xor(s, o, 64);
  if (lane == 0) out[b*3 + c] = s + fc_b[c];
}

extern "C" void kernel_launch(void* const* d_in, const int* in_sizes, int n_in,
                              void* d_out, int out_size, void* d_ws, size_t ws_size,
                              hipStream_t stream)
{
  const float* x        = (const float*)d_in[0];
  const float* exp_w    = (const float*)d_in[1];
  const float* exp_b    = (const float*)d_in[2];
  const float* in_w     = (const float*)d_in[3];
  const float* conv_w   = (const float*)d_in[4];
  const float* conv_b   = (const float*)d_in[5];
  const float* xproj_w  = (const float*)d_in[6];
  const float* dtproj_w = (const float*)d_in[7];
  const float* dtproj_b = (const float*)d_in[8];
  const float* A_log    = (const float*)d_in[9];
  const float* Dp       = (const float*)d_in[10];
  const float* out_w    = (const float*)d_in[11];
  const float* fc_w     = (const float*)d_in[12];
  const float* fc_b     = (const float*)d_in[13];
  float* out = (float*)d_out;

  // Workspace layout (byte offsets), 72 MB total (<= 74.8 proven in R1).
  // 4..20 MB region sequentially reused: xcpre -> dtT -> hf32 (l1 out).
  char* ws = (char*)d_ws;
  _Float16* hf16  = (_Float16*)(ws);                          //  4 MB [4096][512] f16
  float*    xcpre = (float*)   (ws + ((size_t)4  << 20));     // 16 MB [4096][1024]
  float*    dtT   = (float*)   (ws + ((size_t)4  << 20));     // 16 MB [1024][4096] (reuse)
  float*    hf32  = (float*)   (ws + ((size_t)4  << 20));     //  8 MB [4096][512] (reuse, l1)
  float*    xcT   = (float*)   (ws + ((size_t)20 << 20));     // 16 MB [1024][4096]
  _Float16* zsT   = (_Float16*)(ws + ((size_t)36 << 20));     //  8 MB [1024][4096]
  float*    dbc   = (float*)   (ws + ((size_t)44 << 20));     //  2.6 MB [4096][160]
  _Float16* dtr16 = (_Float16*)(ws + ((size_t)47 << 20));     //  0.25 MB [4096][32]
  _Float16* xc16  = (_Float16*)(ws + ((size_t)48 << 20));     //  8 MB [4096][1024]
  _Float16* y16   = (_Float16*)(ws + ((size_t)56 << 20));     //  8 MB [4096][1024]
  _Float16* w16   = (_Float16*)(ws + ((size_t)64 << 20));     //  7.9 MB f16 pool

  _Float16* exp16 = w16;                 // [512][128]
  _Float16* in16  = w16 + 65536;         // [2][2048][512]
  _Float16* xp16  = w16 + 2162688;       // [2][160][1024]
  _Float16* dt16  = w16 + 2490368;       // [2][1024][32]
  _Float16* out16 = w16 + 2555904;       // [2][512][1024]
  _Float16* x16   = w16 + 3604480;       // [4096][128]

  dim3 blk(256);

  // one-shot f16 conversion of all weights + x (4128768 elems, 4032 blocks)
  wcvt_kernel<<<4032, blk, 0, stream>>>(exp_w, in_w, xproj_w, dtproj_w, out_w,
                                        x, w16);

  // expand: hf16 = f16(x @ exp_w^T + exp_b)   [4096,512] K=128. 512 blocks.
  gemm_mfma<64,0,1,0><<<dim3(8,64), blk, 0, stream>>>(x16, 128, exp16, exp_b,
                                                      hf16, 512, 512, 128, 1.f,
                                                      nullptr);

  for (int l = 0; l < 2; ++l) {
    const float is = l ? (1.f / H1_SCALE) : 1.f;     // undo h1 scaling (exact)
    // fused in_proj: xcpre fp32 + zsT f16 (LDS-transposed). N=2048 K=512.
    gemm_mfma<128,0,0,1><<<dim3(16,64), blk, 0, stream>>>(hf16, 512,
                                                          in16 + (size_t)l*1048576,
                                                          nullptr, xcpre, 1024,
                                                          2048, 512, is, zsT);
    // conv + silu -> xcT (fp32, scan) + xc16 (f16, xproj A)
    conv_t_kernel<<<1024, blk, 0, stream>>>(xcpre, conv_w + l*2048, conv_b + l*1024,
                                            xcT, xc16);
    // xproj (MODE 2): dtr16 f16 [4096][32] + dbc fp32 [4096][160]. K=1024.
    gemm_mfma<64,0,0,2><<<dim3(3,64), blk, 0, stream>>>(xc16, 1024,
                                                        xp16 + (size_t)l*163840,
                                                        nullptr, dbc, 160,
                                                        160, 1024, 1.f, dtr16);
    // dtproj (MODE 3): dtT [1024][4096] softplus, LDS-transposed stores. K=32.
    gemm_mfma<64,0,0,3><<<dim3(16,64), blk, 0, stream>>>(dtr16, 32,
                                                         dt16 + (size_t)l*32768,
                                                         dtproj_b + l*1024,
                                                         dtT, 4096, 1024, 32, 1.f,
                                                         nullptr);
    // selective scan; y16 = f16((scan + x*Dp)*silu(z) * 2^14) [bl][d]
    scan_kernel<<<1024, blk, 0, stream>>>(dtT, xcT, zsT, dbc,
                                          A_log + (size_t)l*65536, Dp + l*1024, y16);
    // out_proj: l0 -> hf16 = f16(h1 * 2^8); l1 -> hf32 fp32 for the head.
    if (l == 0)
      gemm_mfma<64,0,1,0><<<dim3(8,64), blk, 0, stream>>>(y16, 1024,
                                                          out16, nullptr,
                                                          hf16, 512, 512, 1024,
                                                          H1_SCALE / Y_SCALE,
                                                          nullptr);
    else
      gemm_mfma<64,0,0,0><<<dim3(8,64), blk, 0, stream>>>(y16, 1024,
                                                          out16 + 524288, nullptr,
                                                          hf32, 512, 512, 1024,
                                                          1.f / Y_SCALE, nullptr);
  }

  head_kernel<<<12, 64, 0, stream>>>(hf32, fc_w, fc_b, out);
}